// Round 9
// baseline (141.629 us; speedup 1.0000x reference)
//
#include <hip/hip_runtime.h>
#include <math.h>

// ConvCapsuleLayer fused, SINGLE-KERNEL edition (no prep_w dispatch — the
// 2-node graph cost ~59 us of the 122 us total in R7).
// Conv as GEMM: M=131072 (b',i,h,w), K=400(pad 416), N=256.
// fp32 emulated: A split exactly as fp16 hi+lo; B = fp16(W) converted ON THE
// FLY from fp32 via v_cvt_pkrtz. B-fragment n-map: n = wv*64 + lrow*4 + nt,
// so one b128 fp32 load W[k][n..n+3] feeds the j-th k-slot of all 4 nt
// fragments (8 loads + 16 pkrtz per chunk). Vote transpose uses a prime-
// stride-17 vt layout (even 8-dword/bank spread for b128 write AND read).
// Batch scramble (faithful to reference reshape): i_x = b'>>1, b_x=((b'&1)<<3)+i.

typedef __attribute__((ext_vector_type(8))) _Float16 half8;
typedef __attribute__((ext_vector_type(4))) _Float16 half4;
typedef __attribute__((ext_vector_type(4))) float f32x4;

typedef decltype(__builtin_amdgcn_cvt_pkrtz(0.f, 0.f)) pk16;
union H8U { half8 h8; pk16 h2[4]; };

// DPP helpers: 0xB1 = quad_perm xor1, 0x4E = xor2, 0x124 = row_ror:4,
// 0x128 = row_ror:8 (== xor8 on the 16-lane ring).
template<int CTRL>
__device__ __forceinline__ float dppf(float x) {
    return __int_as_float(__builtin_amdgcn_update_dpp(
        0, __float_as_int(x), CTRL, 0xF, 0xF, true));
}
__device__ __forceinline__ float sum16(float x) {
    x += dppf<0xB1>(x);
    x += dppf<0x4E>(x);
    x += dppf<0x124>(x);
    x += dppf<0x128>(x);
    return x;
}

#define VTS 17   // vt row stride in dwords (prime -> conflict-free b128 r/w)

__global__ __launch_bounds__(256, 4) void caps_mfma_kernel(
    const float* __restrict__ xg,        // [16,32,32,8,16]
    const float* __restrict__ wg,        // [400][256] fp32
    const float* __restrict__ bg,        // [256]
    float* __restrict__ outg)            // [16,32,32,16,16]
{
    __shared__ __align__(16) char buf[31232];  // xs_h+xs_l / vt (17408 B)
    __shared__ float logit_s[1024];            // [q8][i8][o16]
    __shared__ float route_s[1024];            // [q8][o16][i8] (transposed)

    _Float16* xs_h = (_Float16*)buf;           // [i8][rc 61][c16]
    _Float16* xs_l = (_Float16*)(buf + 15616);
    float*    vt   = (float*)buf;              // votes^T [n256][r16/pass], VTS

    const int t      = threadIdx.x;
    const int blk    = blockIdx.x;             // 2048
    const int wt     = blk & 3;
    const int h0     = (blk >> 2) & 31;
    const int bp     = blk >> 7;
    const int w0base = wt << 3;
    const int i_x    = bp >> 1;
    const int bbase  = (bp & 1) << 3;

    const float bias_r = bg[t];

    // ---- stage x window (60 rc x 16 c x 8 i = 7680 floats) as 1920 float4
    const float4* x4 = (const float4*)xg;
    #pragma unroll
    for (int kk = 0; kk < 8; ++kk) {
        int idx4 = t + (kk << 8);
        if (idx4 < 1920) {
            int c2 = idx4 & 3;                 // c = c2*4
            int i  = (idx4 >> 2) & 7;
            int rc = idx4 >> 5;                // 0..59 = r*12 + cc
            int r  = rc / 12;
            int cc = rc - r * 12;
            int hh = h0 + r - 2;
            int ww = w0base + cc - 2;
            float4 f = make_float4(0.f, 0.f, 0.f, 0.f);
            if (hh >= 0 && hh < 32 && ww >= 0 && ww < 32)
                f = x4[((((bbase + i) * 32 + hh) * 32 + ww) * 8 + i_x) * 4 + c2];
            _Float16 hx = (_Float16)f.x, hy = (_Float16)f.y;
            _Float16 hz = (_Float16)f.z, hw = (_Float16)f.w;
            _Float16 lx = (_Float16)(f.x - (float)hx);
            _Float16 ly = (_Float16)(f.y - (float)hy);
            _Float16 lz = (_Float16)(f.z - (float)hz);
            _Float16 lw = (_Float16)(f.w - (float)hw);
            half4 h4, l4;
            h4.x = hx; h4.y = hy; h4.z = hz; h4.w = hw;
            l4.x = lx; l4.y = ly; l4.z = lz; l4.w = lw;
            int a = i * 976 + rc * 16 + c2 * 4;
            *(half4*)&xs_h[a] = h4;
            *(half4*)&xs_l[a] = l4;
        }
    }
    __syncthreads();

    // ---- MFMA conv
    const int wv   = t >> 6;
    const int lane = t & 63;
    const int lrow = lane & 15;     // m index within 16-tile (and n/4 group)
    const int h8   = lane >> 4;     // k-quarter 0..3
    const int ia   = lrow & 7;      // i of this A row
    const int qh   = lrow >> 3;     // q parity

    f32x4 acc[4][4];
    #pragma unroll
    for (int ms = 0; ms < 4; ++ms)
        #pragma unroll
        for (int nt = 0; nt < 4; ++nt)
            acc[ms][nt] = (f32x4){0.f, 0.f, 0.f, 0.f};

    const f32x4* w4 = (const f32x4*)wg;   // [400][64] f32x4

#define CONV_CHUNK(CH, TAIL)                                                   \
    {                                                                          \
        int k0 = (CH) * 32 + h8 * 8;                                           \
        int p  = k0 >> 4;                                                      \
        int kh = p / 5;                                                        \
        int kw = p - kh * 5;                                                   \
        int c0 = k0 & 15;                                                      \
        int abase = ia * 976 + (kh * 12 + kw + qh) * 16 + c0;                  \
        bool bvalid = !(TAIL) || h8 < 2;                                       \
        f32x4 wj[8];                                                           \
        _Pragma("unroll")                                                      \
        for (int j = 0; j < 8; ++j)                                            \
            wj[j] = bvalid ? w4[(k0 + j) * 64 + wv * 16 + lrow]                \
                           : (f32x4){0.f, 0.f, 0.f, 0.f};                      \
        half8 bhv[4];                                                          \
        _Pragma("unroll")                                                      \
        for (int nt = 0; nt < 4; ++nt) {                                       \
            H8U u;                                                             \
            u.h2[0] = __builtin_amdgcn_cvt_pkrtz(wj[0][nt], wj[1][nt]);        \
            u.h2[1] = __builtin_amdgcn_cvt_pkrtz(wj[2][nt], wj[3][nt]);        \
            u.h2[2] = __builtin_amdgcn_cvt_pkrtz(wj[4][nt], wj[5][nt]);        \
            u.h2[3] = __builtin_amdgcn_cvt_pkrtz(wj[6][nt], wj[7][nt]);        \
            bhv[nt] = u.h8;                                                    \
        }                                                                      \
        _Pragma("unroll")                                                      \
        for (int ms = 0; ms < 4; ++ms) {                                       \
            half8 ahv, alv;                                                    \
            if (bvalid) {                                                      \
                ahv = *(const half8*)&xs_h[abase + ms * 32];                   \
                alv = *(const half8*)&xs_l[abase + ms * 32];                   \
            } else { ahv = (half8)(_Float16)0.f; alv = (half8)(_Float16)0.f; } \
            _Pragma("unroll")                                                  \
            for (int nt = 0; nt < 4; ++nt) {                                   \
                acc[ms][nt] = __builtin_amdgcn_mfma_f32_16x16x32_f16(ahv, bhv[nt], acc[ms][nt], 0, 0, 0); \
                acc[ms][nt] = __builtin_amdgcn_mfma_f32_16x16x32_f16(alv, bhv[nt], acc[ms][nt], 0, 0, 0); \
            }                                                                  \
        }                                                                      \
    }

    #pragma unroll
    for (int ch = 0; ch < 12; ++ch) CONV_CHUNK(ch, false)
    CONV_CHUNK(12, true)
#undef CONV_CHUNK

    // ---- transpose acc -> v[q][i] regs, 4 passes of 16 rows via vt.
    // acc[ms][nt] lane holds D[m-part][n']: od = wv*64 + lrow*4 + nt.
    // Write: vt[od*VTS + h8*4 .. +3]; read: vt[t*VTS + rb*4 + c].
    float v[8][8];
    #pragma unroll
    for (int ms = 0; ms < 4; ++ms) {
        __syncthreads();                       // xs / previous-pass reads done
        #pragma unroll
        for (int nt = 0; nt < 4; ++nt) {
            int n = wv * 64 + lrow * 4 + nt;
            *(f32x4*)&vt[n * VTS + h8 * 4] = acc[ms][nt];
        }
        __syncthreads();
        #pragma unroll
        for (int rb = 0; rb < 4; ++rb) {
            f32x4 x = *(const f32x4*)&vt[t * VTS + rb * 4];
            int q  = ms * 2 + (rb >> 1);
            int ib = (rb & 1) * 4;
            v[q][ib + 0] = x[0];
            v[q][ib + 1] = x[1];
            v[q][ib + 2] = x[2];
            v[q][ib + 3] = x[3];
        }
    }

    // ---- routing from registers: thread t owns od=t (o=t>>4, d=t&15).
    const int o = t >> 4;
    const int d = t & 15;
    const bool b8  = (d & 8) != 0;
    const bool b2v = (d & 2) != 0;
    const bool b1v = (d & 1) != 0;
    const int  im  = (b8 ? 4 : 0) + (b2v ? 2 : 0) + (b1v ? 1 : 0);
    const bool wr  = (d & 4) == 0;
    float act_r[8];

    // agreement: 8 dot-sums over 16 lanes; DPP reduce-scatter, one ds_swizzle
    auto agree = [&](const float* vq, float act, int q, bool first) {
        float p[8];
        #pragma unroll
        for (int i = 0; i < 8; ++i) p[i] = vq[i] * act;
        float s4[4];
        #pragma unroll
        for (int j = 0; j < 4; ++j) {          // exchange lane^8 (ror8)
            float send = b8 ? p[j] : p[j + 4];
            float rcv  = dppf<0x128>(send);
            s4[j] = (b8 ? p[j + 4] : p[j]) + rcv;
        }
        float s2[2];
        #pragma unroll
        for (int j = 0; j < 2; ++j) {          // exchange lane^2
            float send = b2v ? s4[j] : s4[j + 2];
            float rcv  = dppf<0x4E>(send);
            s2[j] = (b2v ? s4[j + 2] : s4[j]) + rcv;
        }
        float send = b1v ? s2[0] : s2[1];      // exchange lane^1
        float rcv  = dppf<0xB1>(send);
        float s1 = (b1v ? s2[1] : s2[0]) + rcv;
        // final: exchange lane^4 (the one non-DPP involution) via ds_swizzle
        float L = s1 + __int_as_float(
            __builtin_amdgcn_ds_swizzle(__float_as_int(s1), 0x101F));
        if (wr) {
            float* dst = &logit_s[q * 128 + im * 16 + o];
            if (first) *dst = L; else *dst += L;
        }
    };

    // ---- it = 0: route == 1/16 exactly; logits written with '=' (no init).
    #pragma unroll
    for (int q = 0; q < 8; ++q) {
        float s = 0.0f;
        #pragma unroll
        for (int i = 0; i < 8; ++i) s += v[q][i];
        float pre = bias_r + 0.0625f * s;
        float n2 = sum16(pre * pre);
        float act = pre * sqrtf(n2) * __builtin_amdgcn_rcpf(1.0f + n2);
        act_r[q] = act;
        agree(v[q], act, q, true);
    }
    __syncthreads();

    // ---- it = 1, 2
    #pragma unroll
    for (int it = 1; it < 3; ++it) {
        {   // parallel softmax: thread -> row r = t>>2 (q=r>>3,i=r&7), 4 o's
            int rr = t >> 2, sq = rr >> 3, si = rr & 7, sj = t & 3;
            f32x4 lg = *(const f32x4*)&logit_s[rr * 16 + sj * 4];
            float m = fmaxf(fmaxf(lg[0], lg[1]), fmaxf(lg[2], lg[3]));
            m = fmaxf(m, dppf<0xB1>(m));       // quad max (4 lanes = same row)
            m = fmaxf(m, dppf<0x4E>(m));
            float e0 = __expf(lg[0] - m), e1 = __expf(lg[1] - m);
            float e2 = __expf(lg[2] - m), e3 = __expf(lg[3] - m);
            float ss = e0 + e1 + e2 + e3;
            ss += dppf<0xB1>(ss);
            ss += dppf<0x4E>(ss);
            float inv = __builtin_amdgcn_rcpf(ss);
            float* rt = &route_s[sq * 128 + si];
            rt[(sj * 4 + 0) * 8] = e0 * inv;
            rt[(sj * 4 + 1) * 8] = e1 * inv;
            rt[(sj * 4 + 2) * 8] = e2 * inv;
            rt[(sj * 4 + 3) * 8] = e3 * inv;
        }
        __syncthreads();

        #pragma unroll
        for (int q = 0; q < 8; ++q) {
            const f32x4* rp = (const f32x4*)&route_s[q * 128 + o * 8];
            f32x4 ra = rp[0], rb2 = rp[1];
            float pre = bias_r
                + ra[0] * v[q][0] + ra[1] * v[q][1] + ra[2] * v[q][2] + ra[3] * v[q][3]
                + rb2[0] * v[q][4] + rb2[1] * v[q][5] + rb2[2] * v[q][6] + rb2[3] * v[q][7];
            float n2 = sum16(pre * pre);
            float act = pre * sqrtf(n2) * __builtin_amdgcn_rcpf(1.0f + n2);
            act_r[q] = act;
            if (it == 1) agree(v[q], act, q, false);
        }
        if (it == 1) __syncthreads();
    }

    // ---- output [b',h0,w0base+q,o,d]
    #pragma unroll
    for (int q = 0; q < 8; ++q)
        outg[((bp * 32 + h0) * 32 + (w0base + q)) * 256 + t] = act_r[q];
}

extern "C" void kernel_launch(void* const* d_in, const int* in_sizes, int n_in,
                              void* d_out, int out_size, void* d_ws, size_t ws_size,
                              hipStream_t stream) {
    const float* x = (const float*)d_in[0];
    const float* w = (const float*)d_in[1];
    const float* b = (const float*)d_in[2];
    float* out = (float*)d_out;

    hipLaunchKernelGGL(caps_mfma_kernel, dim3(2048), dim3(256), 0, stream,
                       x, w, b, out);
}

// Round 10
// 129.248 us; speedup vs baseline: 1.0958x; 1.0958x over previous
//
#include <hip/hip_runtime.h>
#include <math.h>

// ConvCapsuleLayer fused: MFMA 2-term fp16 conv + register-resident routing.
// R10: revert to R7 two-kernel structure (R9 proved the ~55us bench-kernel gap
// is fixed harness overhead, not the prep dispatch; on-the-fly W conv cost
// +24us kernel). New: software-pipelined K-loop — B fragments prefetched one
// chunk ahead (32 MFMAs of latency cover), A fragments one ms-step ahead
// (8 MFMAs). First B prefetch issued before the staging barrier.
// Batch scramble (faithful to reference reshape): i_x = b'>>1, b_x=((b'&1)<<3)+i.

typedef __attribute__((ext_vector_type(8))) _Float16 half8;
typedef __attribute__((ext_vector_type(4))) _Float16 half4;
typedef __attribute__((ext_vector_type(4))) float f32x4;

// W [400][256] fp32 -> Bh [52 kgroups][256 n][8 k] fp16, k padded 400->416
// with zeros (the zero pad also makes tail-chunk B guards unnecessary).
__global__ void prep_w(const float* __restrict__ wg, _Float16* __restrict__ bh) {
    int k = blockIdx.x;        // 0..415
    int n = threadIdx.x;       // 0..255
    float f = (k < 400) ? wg[k * 256 + n] : 0.0f;
    bh[(k >> 3) * 2048 + n * 8 + (k & 7)] = (_Float16)f;
}

// DPP helpers: 0xB1 = quad_perm xor1, 0x4E = xor2, 0x124 = row_ror:4,
// 0x128 = row_ror:8 (== xor8 on the 16-lane ring).
template<int CTRL>
__device__ __forceinline__ float dppf(float x) {
    return __int_as_float(__builtin_amdgcn_update_dpp(
        0, __float_as_int(x), CTRL, 0xF, 0xF, true));
}
__device__ __forceinline__ float sum16(float x) {
    x += dppf<0xB1>(x);
    x += dppf<0x4E>(x);
    x += dppf<0x124>(x);
    x += dppf<0x128>(x);
    return x;
}

__global__ __launch_bounds__(256, 4) void caps_mfma_kernel(
    const float* __restrict__ xg,        // [16,32,32,8,16]
    const _Float16* __restrict__ bhg,    // [52][256][8]
    const float* __restrict__ bg,        // [256]
    float* __restrict__ outg)            // [16,32,32,16,16]
{
    __shared__ __align__(16) char buf[31232];  // xs_h+xs_l / vt (16384)
    __shared__ float logit_s[1024];            // [q8][i8][o16]
    __shared__ float route_s[1024];            // [q8][o16][i8] (transposed)

    _Float16* xs_h = (_Float16*)buf;           // [i8][rc 61][c16]
    _Float16* xs_l = (_Float16*)(buf + 15616);
    float*    vt   = (float*)buf;              // votes^T [n256][r16], swizzled

    const int t      = threadIdx.x;
    const int blk    = blockIdx.x;             // 2048
    const int wt     = blk & 3;
    const int h0     = (blk >> 2) & 31;
    const int bp     = blk >> 7;
    const int w0base = wt << 3;
    const int i_x    = bp >> 1;
    const int bbase  = (bp & 1) << 3;

    const float bias_r = bg[t];

    // wave/lane decomposition (needed for the early B prefetch)
    const int wv   = t >> 6;
    const int lane = t & 63;
    const int lrow = lane & 15;     // m (and n) index within 16-tile
    const int h8   = lane >> 4;     // k-quarter 0..3
    const int ia   = lrow & 7;      // i of this A row
    const int qh   = lrow >> 3;     // q parity

    const half8* bhp = (const half8*)bhg;   // [52][256] half8

    half8 bV[2][4];                 // B double-buffer (chunk-ahead)
    half8 aH[2], aL[2];             // A double-buffer (ms-step-ahead)

#define LOADB(CH, S)                                                     \
    _Pragma("unroll")                                                    \
    for (int nt = 0; nt < 4; ++nt) {                                     \
        int n = wv * 64 + nt * 16 + lrow;                                \
        bV[S][nt] = bhp[((CH) * 4 + h8) * 256 + n];                      \
    }

#define LOADA(CH, MS, S)                                                 \
    {                                                                    \
        int k0 = (CH) * 32 + h8 * 8;                                     \
        int p  = k0 >> 4;                                                \
        int kh = p / 5;                                                  \
        int kw = p - kh * 5;                                             \
        int abase = ia * 976 + (kh * 12 + kw + qh) * 16 + (k0 & 15)      \
                    + (MS) * 32;                                         \
        if ((CH) < 12 || h8 < 2) {                                       \
            aH[S] = *(const half8*)&xs_h[abase];                         \
            aL[S] = *(const half8*)&xs_l[abase];                         \
        } else {                                                         \
            aH[S] = (half8)(_Float16)0.f;                                \
            aL[S] = (half8)(_Float16)0.f;                                \
        }                                                                \
    }

    // issue chunk-0 B prefetch before staging (global, overlaps x staging)
    LOADB(0, 0)

    // ---- stage x window (60 rc x 16 c x 8 i = 7680 floats) as 1920 float4
    const float4* x4 = (const float4*)xg;
    #pragma unroll
    for (int kk = 0; kk < 8; ++kk) {
        int idx4 = t + (kk << 8);
        if (idx4 < 1920) {
            int c2 = idx4 & 3;                 // c = c2*4
            int i  = (idx4 >> 2) & 7;
            int rc = idx4 >> 5;                // 0..59 = r*12 + cc
            int r  = rc / 12;
            int cc = rc - r * 12;
            int hh = h0 + r - 2;
            int ww = w0base + cc - 2;
            float4 f = make_float4(0.f, 0.f, 0.f, 0.f);
            if (hh >= 0 && hh < 32 && ww >= 0 && ww < 32)
                f = x4[((((bbase + i) * 32 + hh) * 32 + ww) * 8 + i_x) * 4 + c2];
            _Float16 hx = (_Float16)f.x, hy = (_Float16)f.y;
            _Float16 hz = (_Float16)f.z, hw = (_Float16)f.w;
            _Float16 lx = (_Float16)(f.x - (float)hx);
            _Float16 ly = (_Float16)(f.y - (float)hy);
            _Float16 lz = (_Float16)(f.z - (float)hz);
            _Float16 lw = (_Float16)(f.w - (float)hw);
            half4 h4, l4;
            h4.x = hx; h4.y = hy; h4.z = hz; h4.w = hw;
            l4.x = lx; l4.y = ly; l4.z = lz; l4.w = lw;
            int a = i * 976 + rc * 16 + c2 * 4;
            *(half4*)&xs_h[a] = h4;
            *(half4*)&xs_l[a] = l4;
        }
    }
    __syncthreads();

    // ---- MFMA conv, software-pipelined
    f32x4 acc[4][4];
    #pragma unroll
    for (int ms = 0; ms < 4; ++ms)
        #pragma unroll
        for (int nt = 0; nt < 4; ++nt)
            acc[ms][nt] = (f32x4){0.f, 0.f, 0.f, 0.f};

    LOADA(0, 0, 0)                   // prologue A

    #pragma unroll
    for (int ch = 0; ch < 13; ++ch) {
        if (ch < 12) LOADB(ch + 1, (ch + 1) & 1)
        #pragma unroll
        for (int ms = 0; ms < 4; ++ms) {
            const int s = (ch * 4 + ms) & 1;
            if (ms < 3) {
                LOADA(ch, ms + 1, s ^ 1)
            } else if (ch < 12) {
                LOADA(ch + 1, 0, s ^ 1)
            }
            #pragma unroll
            for (int nt = 0; nt < 4; ++nt) {
                acc[ms][nt] = __builtin_amdgcn_mfma_f32_16x16x32_f16(
                    aH[s], bV[ch & 1][nt], acc[ms][nt], 0, 0, 0);
                acc[ms][nt] = __builtin_amdgcn_mfma_f32_16x16x32_f16(
                    aL[s], bV[ch & 1][nt], acc[ms][nt], 0, 0, 0);
            }
        }
    }
#undef LOADA
#undef LOADB

    // ---- transpose acc -> v[q][i] regs, 4 passes of 16 rows via 16 KB vt.
    // Pass ms: rows r_local = h8*4+reg; vt dword addr = n*16 + ((rb^(n&3))<<2).
    float v[8][8];
    #pragma unroll
    for (int ms = 0; ms < 4; ++ms) {
        __syncthreads();                       // xs / previous-pass reads done
        #pragma unroll
        for (int nt = 0; nt < 4; ++nt) {
            int n = wv * 64 + nt * 16 + lrow;
            *(f32x4*)&vt[n * 16 + ((h8 ^ (n & 3)) << 2)] = acc[ms][nt];
        }
        __syncthreads();
        #pragma unroll
        for (int rb = 0; rb < 4; ++rb) {
            f32x4 x = *(const f32x4*)&vt[t * 16 + ((rb ^ (t & 3)) << 2)];
            int q  = ms * 2 + (rb >> 1);
            int ib = (rb & 1) * 4;
            v[q][ib + 0] = x[0];
            v[q][ib + 1] = x[1];
            v[q][ib + 2] = x[2];
            v[q][ib + 3] = x[3];
        }
    }

    // ---- routing from registers: thread t owns od=t (o=t>>4, d=t&15).
    const int o = t >> 4;
    const int d = t & 15;
    const bool b8  = (d & 8) != 0;
    const bool b2v = (d & 2) != 0;
    const bool b1v = (d & 1) != 0;
    const int  im  = (b8 ? 4 : 0) + (b2v ? 2 : 0) + (b1v ? 1 : 0);
    const bool wr  = (d & 4) == 0;
    float act_r[8];

    // agreement: 8 dot-sums over 16 lanes; DPP reduce-scatter, one ds_swizzle
    auto agree = [&](const float* vq, float act, int q, bool first) {
        float p[8];
        #pragma unroll
        for (int i = 0; i < 8; ++i) p[i] = vq[i] * act;
        float s4[4];
        #pragma unroll
        for (int j = 0; j < 4; ++j) {          // exchange lane^8 (ror8)
            float send = b8 ? p[j] : p[j + 4];
            float rcv  = dppf<0x128>(send);
            s4[j] = (b8 ? p[j + 4] : p[j]) + rcv;
        }
        float s2[2];
        #pragma unroll
        for (int j = 0; j < 2; ++j) {          // exchange lane^2
            float send = b2v ? s4[j] : s4[j + 2];
            float rcv  = dppf<0x4E>(send);
            s2[j] = (b2v ? s4[j + 2] : s4[j]) + rcv;
        }
        float send = b1v ? s2[0] : s2[1];      // exchange lane^1
        float rcv  = dppf<0xB1>(send);
        float s1 = (b1v ? s2[1] : s2[0]) + rcv;
        // final: exchange lane^4 (the one non-DPP involution) via ds_swizzle
        float L = s1 + __int_as_float(
            __builtin_amdgcn_ds_swizzle(__float_as_int(s1), 0x101F));
        if (wr) {
            float* dst = &logit_s[q * 128 + im * 16 + o];
            if (first) *dst = L; else *dst += L;
        }
    };

    // ---- it = 0: route == 1/16 exactly; logits written with '=' (no init).
    #pragma unroll
    for (int q = 0; q < 8; ++q) {
        float s = 0.0f;
        #pragma unroll
        for (int i = 0; i < 8; ++i) s += v[q][i];
        float pre = bias_r + 0.0625f * s;
        float n2 = sum16(pre * pre);
        float act = pre * sqrtf(n2) * __builtin_amdgcn_rcpf(1.0f + n2);
        act_r[q] = act;
        agree(v[q], act, q, true);
    }
    __syncthreads();

    // ---- it = 1, 2
    #pragma unroll
    for (int it = 1; it < 3; ++it) {
        {   // parallel softmax: thread -> row r = t>>2 (q=r>>3,i=r&7), 4 o's
            int rr = t >> 2, sq = rr >> 3, si = rr & 7, sj = t & 3;
            f32x4 lg = *(const f32x4*)&logit_s[rr * 16 + sj * 4];
            float m = fmaxf(fmaxf(lg[0], lg[1]), fmaxf(lg[2], lg[3]));
            m = fmaxf(m, dppf<0xB1>(m));       // quad max (4 lanes = same row)
            m = fmaxf(m, dppf<0x4E>(m));
            float e0 = __expf(lg[0] - m), e1 = __expf(lg[1] - m);
            float e2 = __expf(lg[2] - m), e3 = __expf(lg[3] - m);
            float ss = e0 + e1 + e2 + e3;
            ss += dppf<0xB1>(ss);
            ss += dppf<0x4E>(ss);
            float inv = __builtin_amdgcn_rcpf(ss);
            float* rt = &route_s[sq * 128 + si];
            rt[(sj * 4 + 0) * 8] = e0 * inv;
            rt[(sj * 4 + 1) * 8] = e1 * inv;
            rt[(sj * 4 + 2) * 8] = e2 * inv;
            rt[(sj * 4 + 3) * 8] = e3 * inv;
        }
        __syncthreads();

        #pragma unroll
        for (int q = 0; q < 8; ++q) {
            const f32x4* rp = (const f32x4*)&route_s[q * 128 + o * 8];
            f32x4 ra = rp[0], rb2 = rp[1];
            float pre = bias_r
                + ra[0] * v[q][0] + ra[1] * v[q][1] + ra[2] * v[q][2] + ra[3] * v[q][3]
                + rb2[0] * v[q][4] + rb2[1] * v[q][5] + rb2[2] * v[q][6] + rb2[3] * v[q][7];
            float n2 = sum16(pre * pre);
            float act = pre * sqrtf(n2) * __builtin_amdgcn_rcpf(1.0f + n2);
            act_r[q] = act;
            if (it == 1) agree(v[q], act, q, false);
        }
        if (it == 1) __syncthreads();
    }

    // ---- output [b',h0,w0base+q,o,d]
    #pragma unroll
    for (int q = 0; q < 8; ++q)
        outg[((bp * 32 + h0) * 32 + (w0base + q)) * 256 + t] = act_r[q];
}

extern "C" void kernel_launch(void* const* d_in, const int* in_sizes, int n_in,
                              void* d_out, int out_size, void* d_ws, size_t ws_size,
                              hipStream_t stream) {
    const float* x = (const float*)d_in[0];
    const float* w = (const float*)d_in[1];
    const float* b = (const float*)d_in[2];
    float* out = (float*)d_out;

    _Float16* bh = (_Float16*)d_ws;            // 52*256*8*2 = 106496 B

    hipLaunchKernelGGL(prep_w, dim3(416), dim3(256), 0, stream, w, bh);
    hipLaunchKernelGGL(caps_mfma_kernel, dim3(2048), dim3(256), 0, stream,
                       x, bh, b, out);
}

// Round 11
// 125.468 us; speedup vs baseline: 1.1288x; 1.0301x over previous
//
#include <hip/hip_runtime.h>
#include <math.h>

// ConvCapsuleLayer fused: MFMA 2-term fp16 conv + register-resident routing.
// R11: R10's software pipeline, spill-proofed. R10 failed because
// __launch_bounds__(256,4) caps the unified VGPR+AGPR file at 128 (R7 sat at
// exactly 64+64); the pipeline registers spilled to scratch (+83 MB HBM).
// Fix: bounds (256,3) (~170 regs; achieved occupancy was ~3 blocks/CU anyway)
// + named-variable double buffers (no arrays indexed by loop-carried values).
// Schedule: B prefetched one chunk ahead (32 MFMAs cover), A one ms-step
// ahead (8 MFMAs cover). First B prefetch overlaps x staging.
// Batch scramble (faithful to reference reshape): i_x = b'>>1, b_x=((b'&1)<<3)+i.

typedef __attribute__((ext_vector_type(8))) _Float16 half8;
typedef __attribute__((ext_vector_type(4))) _Float16 half4;
typedef __attribute__((ext_vector_type(4))) float f32x4;

// W [400][256] fp32 -> Bh [52 kgroups][256 n][8 k] fp16, k padded 400->416
// with zeros (zero pad makes tail-chunk B guards unnecessary).
__global__ void prep_w(const float* __restrict__ wg, _Float16* __restrict__ bh) {
    int k = blockIdx.x;        // 0..415
    int n = threadIdx.x;       // 0..255
    float f = (k < 400) ? wg[k * 256 + n] : 0.0f;
    bh[(k >> 3) * 2048 + n * 8 + (k & 7)] = (_Float16)f;
}

// DPP helpers: 0xB1 = quad_perm xor1, 0x4E = xor2, 0x124 = row_ror:4,
// 0x128 = row_ror:8 (== xor8 on the 16-lane ring).
template<int CTRL>
__device__ __forceinline__ float dppf(float x) {
    return __int_as_float(__builtin_amdgcn_update_dpp(
        0, __float_as_int(x), CTRL, 0xF, 0xF, true));
}
__device__ __forceinline__ float sum16(float x) {
    x += dppf<0xB1>(x);
    x += dppf<0x4E>(x);
    x += dppf<0x124>(x);
    x += dppf<0x128>(x);
    return x;
}

__global__ __launch_bounds__(256, 3) void caps_mfma_kernel(
    const float* __restrict__ xg,        // [16,32,32,8,16]
    const _Float16* __restrict__ bhg,    // [52][256][8]
    const float* __restrict__ bg,        // [256]
    float* __restrict__ outg)            // [16,32,32,16,16]
{
    __shared__ __align__(16) char buf[31232];  // xs_h+xs_l / vt (16384)
    __shared__ float logit_s[1024];            // [q8][i8][o16]
    __shared__ float route_s[1024];            // [q8][o16][i8] (transposed)

    _Float16* xs_h = (_Float16*)buf;           // [i8][rc 61][c16]
    _Float16* xs_l = (_Float16*)(buf + 15616);
    float*    vt   = (float*)buf;              // votes^T [n256][r16], swizzled

    const int t      = threadIdx.x;
    const int blk    = blockIdx.x;             // 2048
    const int wt     = blk & 3;
    const int h0     = (blk >> 2) & 31;
    const int bp     = blk >> 7;
    const int w0base = wt << 3;
    const int i_x    = bp >> 1;
    const int bbase  = (bp & 1) << 3;

    const float bias_r = bg[t];

    const int wv   = t >> 6;
    const int lane = t & 63;
    const int lrow = lane & 15;     // m (and n) index within 16-tile
    const int h8   = lane >> 4;     // k-quarter 0..3
    const int ia   = lrow & 7;      // i of this A row
    const int qh   = lrow >> 3;     // q parity

    const half8* bhp = (const half8*)bhg;   // [52][256] half8

    half8 bE0, bE1, bE2, bE3;       // B bank E (even chunks)
    half8 bO0, bO1, bO2, bO3;       // B bank O (odd chunks)
    half8 aHc, aLc, aHn, aLn;       // A ping-pong

#define LOADB(CH, B0, B1, B2, B3)                                        \
    {                                                                    \
        int gb = ((CH) * 4 + h8) * 256 + wv * 64 + lrow;                 \
        B0 = bhp[gb];                                                    \
        B1 = bhp[gb + 16];                                               \
        B2 = bhp[gb + 32];                                               \
        B3 = bhp[gb + 48];                                               \
    }

#define LOADA(CH, MS, AH, AL)                                            \
    {                                                                    \
        int k0 = (CH) * 32 + h8 * 8;                                     \
        int p  = k0 >> 4;                                                \
        int kh = p / 5;                                                  \
        int kw = p - kh * 5;                                             \
        int ab = ia * 976 + (kh * 12 + kw + qh) * 16 + (k0 & 15)         \
                 + (MS) * 32;                                            \
        if ((CH) < 12 || h8 < 2) {                                       \
            AH = *(const half8*)&xs_h[ab];                               \
            AL = *(const half8*)&xs_l[ab];                               \
        } else {                                                         \
            AH = (half8)(_Float16)0.f;                                   \
            AL = (half8)(_Float16)0.f;                                   \
        }                                                                \
    }

#define MFMA8(MS, AH, AL, B0, B1, B2, B3)                                \
    acc[MS][0] = __builtin_amdgcn_mfma_f32_16x16x32_f16(AH, B0, acc[MS][0], 0, 0, 0); \
    acc[MS][1] = __builtin_amdgcn_mfma_f32_16x16x32_f16(AH, B1, acc[MS][1], 0, 0, 0); \
    acc[MS][2] = __builtin_amdgcn_mfma_f32_16x16x32_f16(AH, B2, acc[MS][2], 0, 0, 0); \
    acc[MS][3] = __builtin_amdgcn_mfma_f32_16x16x32_f16(AH, B3, acc[MS][3], 0, 0, 0); \
    acc[MS][0] = __builtin_amdgcn_mfma_f32_16x16x32_f16(AL, B0, acc[MS][0], 0, 0, 0); \
    acc[MS][1] = __builtin_amdgcn_mfma_f32_16x16x32_f16(AL, B1, acc[MS][1], 0, 0, 0); \
    acc[MS][2] = __builtin_amdgcn_mfma_f32_16x16x32_f16(AL, B2, acc[MS][2], 0, 0, 0); \
    acc[MS][3] = __builtin_amdgcn_mfma_f32_16x16x32_f16(AL, B3, acc[MS][3], 0, 0, 0);

// one ms-step: prefetch next A, then 8 MFMAs with current A
#define STEP(MS, AH, AL, AHN, ALN, NCH, NMS, B0, B1, B2, B3)             \
    LOADA(NCH, NMS, AHN, ALN)                                            \
    MFMA8(MS, AH, AL, B0, B1, B2, B3)

// full chunk: prefetch next chunk's B into the other bank, 4 ms-steps
#define CHUNK(CH, U0, U1, U2, U3, L0, L1, L2, L3, LCH)                   \
    LOADB(LCH, L0, L1, L2, L3)                                           \
    STEP(0, aHc, aLc, aHn, aLn, CH, 1, U0, U1, U2, U3)                   \
    STEP(1, aHn, aLn, aHc, aLc, CH, 2, U0, U1, U2, U3)                   \
    STEP(2, aHc, aLc, aHn, aLn, CH, 3, U0, U1, U2, U3)                   \
    STEP(3, aHn, aLn, aHc, aLc, (CH) + 1, 0, U0, U1, U2, U3)

    // issue chunk-0 B prefetch before staging (global, overlaps x staging)
    LOADB(0, bE0, bE1, bE2, bE3)

    // ---- stage x window (60 rc x 16 c x 8 i = 7680 floats) as 1920 float4
    const float4* x4 = (const float4*)xg;
    #pragma unroll
    for (int kk = 0; kk < 8; ++kk) {
        int idx4 = t + (kk << 8);
        if (idx4 < 1920) {
            int c2 = idx4 & 3;                 // c = c2*4
            int i  = (idx4 >> 2) & 7;
            int rc = idx4 >> 5;                // 0..59 = r*12 + cc
            int r  = rc / 12;
            int cc = rc - r * 12;
            int hh = h0 + r - 2;
            int ww = w0base + cc - 2;
            float4 f = make_float4(0.f, 0.f, 0.f, 0.f);
            if (hh >= 0 && hh < 32 && ww >= 0 && ww < 32)
                f = x4[((((bbase + i) * 32 + hh) * 32 + ww) * 8 + i_x) * 4 + c2];
            _Float16 hx = (_Float16)f.x, hy = (_Float16)f.y;
            _Float16 hz = (_Float16)f.z, hw = (_Float16)f.w;
            _Float16 lx = (_Float16)(f.x - (float)hx);
            _Float16 ly = (_Float16)(f.y - (float)hy);
            _Float16 lz = (_Float16)(f.z - (float)hz);
            _Float16 lw = (_Float16)(f.w - (float)hw);
            half4 h4, l4;
            h4.x = hx; h4.y = hy; h4.z = hz; h4.w = hw;
            l4.x = lx; l4.y = ly; l4.z = lz; l4.w = lw;
            int a = i * 976 + rc * 16 + c2 * 4;
            *(half4*)&xs_h[a] = h4;
            *(half4*)&xs_l[a] = l4;
        }
    }
    __syncthreads();

    // ---- MFMA conv, software-pipelined (named regs only)
    f32x4 acc[4][4];
    #pragma unroll
    for (int ms = 0; ms < 4; ++ms)
        #pragma unroll
        for (int nt = 0; nt < 4; ++nt)
            acc[ms][nt] = (f32x4){0.f, 0.f, 0.f, 0.f};

    LOADA(0, 0, aHc, aLc)            // prologue A

    #pragma unroll
    for (int cp = 0; cp < 6; ++cp) {
        const int che = 2 * cp;
        CHUNK(che,     bE0, bE1, bE2, bE3, bO0, bO1, bO2, bO3, che + 1)
        CHUNK(che + 1, bO0, bO1, bO2, bO3, bE0, bE1, bE2, bE3, che + 2)
    }
    // tail chunk 12 (uses bank E, loaded during chunk 11; no further B)
    STEP(0, aHc, aLc, aHn, aLn, 12, 1, bE0, bE1, bE2, bE3)
    STEP(1, aHn, aLn, aHc, aLc, 12, 2, bE0, bE1, bE2, bE3)
    STEP(2, aHc, aLc, aHn, aLn, 12, 3, bE0, bE1, bE2, bE3)
    MFMA8(3, aHn, aLn, bE0, bE1, bE2, bE3)

#undef CHUNK
#undef STEP
#undef MFMA8
#undef LOADA
#undef LOADB

    // ---- transpose acc -> v[q][i] regs, 4 passes of 16 rows via 16 KB vt.
    // Pass ms: rows r_local = h8*4+reg; vt dword addr = n*16 + ((rb^(n&3))<<2).
    float v[8][8];
    #pragma unroll
    for (int ms = 0; ms < 4; ++ms) {
        __syncthreads();                       // xs / previous-pass reads done
        #pragma unroll
        for (int nt = 0; nt < 4; ++nt) {
            int n = wv * 64 + nt * 16 + lrow;
            *(f32x4*)&vt[n * 16 + ((h8 ^ (n & 3)) << 2)] = acc[ms][nt];
        }
        __syncthreads();
        #pragma unroll
        for (int rb = 0; rb < 4; ++rb) {
            f32x4 x = *(const f32x4*)&vt[t * 16 + ((rb ^ (t & 3)) << 2)];
            int q  = ms * 2 + (rb >> 1);
            int ib = (rb & 1) * 4;
            v[q][ib + 0] = x[0];
            v[q][ib + 1] = x[1];
            v[q][ib + 2] = x[2];
            v[q][ib + 3] = x[3];
        }
    }

    // ---- routing from registers: thread t owns od=t (o=t>>4, d=t&15).
    const int o = t >> 4;
    const int d = t & 15;
    const bool b8  = (d & 8) != 0;
    const bool b2v = (d & 2) != 0;
    const bool b1v = (d & 1) != 0;
    const int  im  = (b8 ? 4 : 0) + (b2v ? 2 : 0) + (b1v ? 1 : 0);
    const bool wr  = (d & 4) == 0;
    float act_r[8];

    // agreement: 8 dot-sums over 16 lanes; DPP reduce-scatter, one ds_swizzle
    auto agree = [&](const float* vq, float act, int q, bool first) {
        float p[8];
        #pragma unroll
        for (int i = 0; i < 8; ++i) p[i] = vq[i] * act;
        float s4[4];
        #pragma unroll
        for (int j = 0; j < 4; ++j) {          // exchange lane^8 (ror8)
            float send = b8 ? p[j] : p[j + 4];
            float rcv  = dppf<0x128>(send);
            s4[j] = (b8 ? p[j + 4] : p[j]) + rcv;
        }
        float s2[2];
        #pragma unroll
        for (int j = 0; j < 2; ++j) {          // exchange lane^2
            float send = b2v ? s4[j] : s4[j + 2];
            float rcv  = dppf<0x4E>(send);
            s2[j] = (b2v ? s4[j + 2] : s4[j]) + rcv;
        }
        float send = b1v ? s2[0] : s2[1];      // exchange lane^1
        float rcv  = dppf<0xB1>(send);
        float s1 = (b1v ? s2[1] : s2[0]) + rcv;
        // final: exchange lane^4 (the one non-DPP involution) via ds_swizzle
        float L = s1 + __int_as_float(
            __builtin_amdgcn_ds_swizzle(__float_as_int(s1), 0x101F));
        if (wr) {
            float* dst = &logit_s[q * 128 + im * 16 + o];
            if (first) *dst = L; else *dst += L;
        }
    };

    // ---- it = 0: route == 1/16 exactly; logits written with '=' (no init).
    #pragma unroll
    for (int q = 0; q < 8; ++q) {
        float s = 0.0f;
        #pragma unroll
        for (int i = 0; i < 8; ++i) s += v[q][i];
        float pre = bias_r + 0.0625f * s;
        float n2 = sum16(pre * pre);
        float act = pre * sqrtf(n2) * __builtin_amdgcn_rcpf(1.0f + n2);
        act_r[q] = act;
        agree(v[q], act, q, true);
    }
    __syncthreads();

    // ---- it = 1, 2
    #pragma unroll
    for (int it = 1; it < 3; ++it) {
        {   // parallel softmax: thread -> row r = t>>2 (q=r>>3,i=r&7), 4 o's
            int rr = t >> 2, sq = rr >> 3, si = rr & 7, sj = t & 3;
            f32x4 lg = *(const f32x4*)&logit_s[rr * 16 + sj * 4];
            float m = fmaxf(fmaxf(lg[0], lg[1]), fmaxf(lg[2], lg[3]));
            m = fmaxf(m, dppf<0xB1>(m));       // quad max (4 lanes = same row)
            m = fmaxf(m, dppf<0x4E>(m));
            float e0 = __expf(lg[0] - m), e1 = __expf(lg[1] - m);
            float e2 = __expf(lg[2] - m), e3 = __expf(lg[3] - m);
            float ss = e0 + e1 + e2 + e3;
            ss += dppf<0xB1>(ss);
            ss += dppf<0x4E>(ss);
            float inv = __builtin_amdgcn_rcpf(ss);
            float* rt = &route_s[sq * 128 + si];
            rt[(sj * 4 + 0) * 8] = e0 * inv;
            rt[(sj * 4 + 1) * 8] = e1 * inv;
            rt[(sj * 4 + 2) * 8] = e2 * inv;
            rt[(sj * 4 + 3) * 8] = e3 * inv;
        }
        __syncthreads();

        #pragma unroll
        for (int q = 0; q < 8; ++q) {
            const f32x4* rp = (const f32x4*)&route_s[q * 128 + o * 8];
            f32x4 ra = rp[0], rb2 = rp[1];
            float pre = bias_r
                + ra[0] * v[q][0] + ra[1] * v[q][1] + ra[2] * v[q][2] + ra[3] * v[q][3]
                + rb2[0] * v[q][4] + rb2[1] * v[q][5] + rb2[2] * v[q][6] + rb2[3] * v[q][7];
            float n2 = sum16(pre * pre);
            float act = pre * sqrtf(n2) * __builtin_amdgcn_rcpf(1.0f + n2);
            act_r[q] = act;
            if (it == 1) agree(v[q], act, q, false);
        }
        if (it == 1) __syncthreads();
    }

    // ---- output [b',h0,w0base+q,o,d]
    #pragma unroll
    for (int q = 0; q < 8; ++q)
        outg[((bp * 32 + h0) * 32 + (w0base + q)) * 256 + t] = act_r[q];
}

extern "C" void kernel_launch(void* const* d_in, const int* in_sizes, int n_in,
                              void* d_out, int out_size, void* d_ws, size_t ws_size,
                              hipStream_t stream) {
    const float* x = (const float*)d_in[0];
    const float* w = (const float*)d_in[1];
    const float* b = (const float*)d_in[2];
    float* out = (float*)d_out;

    _Float16* bh = (_Float16*)d_ws;            // 52*256*8*2 = 106496 B

    hipLaunchKernelGGL(prep_w, dim3(416), dim3(256), 0, stream, w, bh);
    hipLaunchKernelGGL(caps_mfma_kernel, dim3(2048), dim3(256), 0, stream,
                       x, bh, b, out);
}

// Round 12
// 111.561 us; speedup vs baseline: 1.2695x; 1.1247x over previous
//
#include <hip/hip_runtime.h>
#include <math.h>

// ConvCapsuleLayer fused: MFMA single-fp16 conv + register-resident routing.
// R12: revert to R7's unpipelined structure (R11 proved explicit SW pipelining
// is neutral-negative here) and HALVE the MFMA work: votes = fp16(x)*fp16(W),
// single MFMA per slot. Error budget: absmax has been pinned at 2^-8=3.9e-3
// (routing noise) since R2's exact-fp32 conv; fp16 A+B rounding adds ~1e-3
// vote error vs the 1.76e-2 threshold. MFMA work 55.8 -> 27.9 GF.
// Batch scramble (faithful to reference reshape): i_x = b'>>1, b_x=((b'&1)<<3)+i.

typedef __attribute__((ext_vector_type(8))) _Float16 half8;
typedef __attribute__((ext_vector_type(4))) _Float16 half4;
typedef __attribute__((ext_vector_type(4))) float f32x4;

// W [400][256] fp32 -> Bh [52 kgroups][256 n][8 k] fp16, k padded 400->416.
__global__ void prep_w(const float* __restrict__ wg, _Float16* __restrict__ bh) {
    int k = blockIdx.x;        // 0..415
    int n = threadIdx.x;       // 0..255
    float f = (k < 400) ? wg[k * 256 + n] : 0.0f;
    bh[(k >> 3) * 2048 + n * 8 + (k & 7)] = (_Float16)f;
}

// DPP helpers: 0xB1 = quad_perm xor1, 0x4E = xor2, 0x124 = row_ror:4,
// 0x128 = row_ror:8 (== xor8 on the 16-lane ring).
template<int CTRL>
__device__ __forceinline__ float dppf(float x) {
    return __int_as_float(__builtin_amdgcn_update_dpp(
        0, __float_as_int(x), CTRL, 0xF, 0xF, true));
}
__device__ __forceinline__ float sum16(float x) {
    x += dppf<0xB1>(x);
    x += dppf<0x4E>(x);
    x += dppf<0x124>(x);
    x += dppf<0x128>(x);
    return x;
}

__global__ __launch_bounds__(256, 4) void caps_mfma_kernel(
    const float* __restrict__ xg,        // [16,32,32,8,16]
    const _Float16* __restrict__ bhg,    // [52][256][8]
    const float* __restrict__ bg,        // [256]
    float* __restrict__ outg)            // [16,32,32,16,16]
{
    __shared__ __align__(16) char buf[16384];  // xs (15616 B) / vt (16384 B)
    __shared__ float logit_s[1024];            // [q8][i8][o16]
    __shared__ float route_s[1024];            // [q8][o16][i8] (transposed)

    _Float16* xs = (_Float16*)buf;             // [i8][rc 61][c16]
    float*    vt = (float*)buf;                // votes^T [n256][r16], swizzled

    const int t      = threadIdx.x;
    const int blk    = blockIdx.x;             // 2048
    const int wt     = blk & 3;
    const int h0     = (blk >> 2) & 31;
    const int bp     = blk >> 7;
    const int w0base = wt << 3;
    const int i_x    = bp >> 1;
    const int bbase  = (bp & 1) << 3;

    const float bias_r = bg[t];

    // ---- stage x window (60 rc x 16 c x 8 i = 7680 floats) as 1920 float4
    const float4* x4 = (const float4*)xg;
    #pragma unroll
    for (int kk = 0; kk < 8; ++kk) {
        int idx4 = t + (kk << 8);
        if (idx4 < 1920) {
            int c2 = idx4 & 3;                 // c = c2*4
            int i  = (idx4 >> 2) & 7;
            int rc = idx4 >> 5;                // 0..59 = r*12 + cc
            int r  = rc / 12;
            int cc = rc - r * 12;
            int hh = h0 + r - 2;
            int ww = w0base + cc - 2;
            float4 f = make_float4(0.f, 0.f, 0.f, 0.f);
            if (hh >= 0 && hh < 32 && ww >= 0 && ww < 32)
                f = x4[((((bbase + i) * 32 + hh) * 32 + ww) * 8 + i_x) * 4 + c2];
            half4 h4;
            h4.x = (_Float16)f.x; h4.y = (_Float16)f.y;
            h4.z = (_Float16)f.z; h4.w = (_Float16)f.w;
            *(half4*)&xs[i * 976 + rc * 16 + c2 * 4] = h4;
        }
    }
    __syncthreads();

    // ---- MFMA conv (unpipelined chunk loop, R7 style)
    const int wv   = t >> 6;
    const int lane = t & 63;
    const int lrow = lane & 15;     // m (and n) index within 16-tile
    const int h8   = lane >> 4;     // k-quarter 0..3
    const int ia   = lrow & 7;      // i of this A row
    const int qh   = lrow >> 3;     // q parity

    f32x4 acc[4][4];
    #pragma unroll
    for (int ms = 0; ms < 4; ++ms)
        #pragma unroll
        for (int nt = 0; nt < 4; ++nt)
            acc[ms][nt] = (f32x4){0.f, 0.f, 0.f, 0.f};

    const half8* bhp = (const half8*)bhg;   // [52][256] half8

#define CONV_CHUNK(CH, TAIL)                                                   \
    {                                                                          \
        int k0 = (CH) * 32 + h8 * 8;                                           \
        int p  = k0 >> 4;                                                      \
        int kh = p / 5;                                                        \
        int kw = p - kh * 5;                                                   \
        int abase = ia * 976 + (kh * 12 + kw + qh) * 16 + (k0 & 15);           \
        int g = (CH) * 4 + h8;                                                 \
        half8 bhv[4];                                                          \
        _Pragma("unroll")                                                      \
        for (int nt = 0; nt < 4; ++nt)                                         \
            bhv[nt] = bhp[g * 256 + wv * 64 + nt * 16 + lrow];                 \
        _Pragma("unroll")                                                      \
        for (int ms = 0; ms < 4; ++ms) {                                       \
            half8 ahv;                                                         \
            if (!(TAIL) || h8 < 2) ahv = *(const half8*)&xs[abase + ms * 32];  \
            else                   ahv = (half8)(_Float16)0.f;                 \
            _Pragma("unroll")                                                  \
            for (int nt = 0; nt < 4; ++nt)                                     \
                acc[ms][nt] = __builtin_amdgcn_mfma_f32_16x16x32_f16(          \
                    ahv, bhv[nt], acc[ms][nt], 0, 0, 0);                       \
        }                                                                      \
    }

    #pragma unroll
    for (int ch = 0; ch < 12; ++ch) CONV_CHUNK(ch, false)
    CONV_CHUNK(12, true)
#undef CONV_CHUNK

    // ---- transpose acc -> v[q][i] regs, 4 passes of 16 rows via 16 KB vt.
    // Pass ms: rows r_local = h8*4+reg; vt dword addr = n*16 + ((rb^(n&3))<<2).
    float v[8][8];
    #pragma unroll
    for (int ms = 0; ms < 4; ++ms) {
        __syncthreads();                       // xs / previous-pass reads done
        #pragma unroll
        for (int nt = 0; nt < 4; ++nt) {
            int n = wv * 64 + nt * 16 + lrow;
            *(f32x4*)&vt[n * 16 + ((h8 ^ (n & 3)) << 2)] = acc[ms][nt];
        }
        __syncthreads();
        #pragma unroll
        for (int rb = 0; rb < 4; ++rb) {
            f32x4 x = *(const f32x4*)&vt[t * 16 + ((rb ^ (t & 3)) << 2)];
            int q  = ms * 2 + (rb >> 1);
            int ib = (rb & 1) * 4;
            v[q][ib + 0] = x[0];
            v[q][ib + 1] = x[1];
            v[q][ib + 2] = x[2];
            v[q][ib + 3] = x[3];
        }
    }

    // ---- routing from registers: thread t owns od=t (o=t>>4, d=t&15).
    const int o = t >> 4;
    const int d = t & 15;
    const bool b8  = (d & 8) != 0;
    const bool b2v = (d & 2) != 0;
    const bool b1v = (d & 1) != 0;
    const int  im  = (b8 ? 4 : 0) + (b2v ? 2 : 0) + (b1v ? 1 : 0);
    const bool wr  = (d & 4) == 0;
    float act_r[8];

    // agreement: 8 dot-sums over 16 lanes; DPP reduce-scatter, one ds_swizzle
    auto agree = [&](const float* vq, float act, int q, bool first) {
        float p[8];
        #pragma unroll
        for (int i = 0; i < 8; ++i) p[i] = vq[i] * act;
        float s4[4];
        #pragma unroll
        for (int j = 0; j < 4; ++j) {          // exchange lane^8 (ror8)
            float send = b8 ? p[j] : p[j + 4];
            float rcv  = dppf<0x128>(send);
            s4[j] = (b8 ? p[j + 4] : p[j]) + rcv;
        }
        float s2[2];
        #pragma unroll
        for (int j = 0; j < 2; ++j) {          // exchange lane^2
            float send = b2v ? s4[j] : s4[j + 2];
            float rcv  = dppf<0x4E>(send);
            s2[j] = (b2v ? s4[j + 2] : s4[j]) + rcv;
        }
        float send = b1v ? s2[0] : s2[1];      // exchange lane^1
        float rcv  = dppf<0xB1>(send);
        float s1 = (b1v ? s2[1] : s2[0]) + rcv;
        // final: exchange lane^4 (the one non-DPP involution) via ds_swizzle
        float L = s1 + __int_as_float(
            __builtin_amdgcn_ds_swizzle(__float_as_int(s1), 0x101F));
        if (wr) {
            float* dst = &logit_s[q * 128 + im * 16 + o];
            if (first) *dst = L; else *dst += L;
        }
    };

    // ---- it = 0: route == 1/16 exactly; logits written with '=' (no init).
    #pragma unroll
    for (int q = 0; q < 8; ++q) {
        float s = 0.0f;
        #pragma unroll
        for (int i = 0; i < 8; ++i) s += v[q][i];
        float pre = bias_r + 0.0625f * s;
        float n2 = sum16(pre * pre);
        float act = pre * sqrtf(n2) * __builtin_amdgcn_rcpf(1.0f + n2);
        act_r[q] = act;
        agree(v[q], act, q, true);
    }
    __syncthreads();

    // ---- it = 1, 2
    #pragma unroll
    for (int it = 1; it < 3; ++it) {
        {   // parallel softmax: thread -> row r = t>>2 (q=r>>3,i=r&7), 4 o's
            int rr = t >> 2, sq = rr >> 3, si = rr & 7, sj = t & 3;
            f32x4 lg = *(const f32x4*)&logit_s[rr * 16 + sj * 4];
            float m = fmaxf(fmaxf(lg[0], lg[1]), fmaxf(lg[2], lg[3]));
            m = fmaxf(m, dppf<0xB1>(m));       // quad max (4 lanes = same row)
            m = fmaxf(m, dppf<0x4E>(m));
            float e0 = __expf(lg[0] - m), e1 = __expf(lg[1] - m);
            float e2 = __expf(lg[2] - m), e3 = __expf(lg[3] - m);
            float ss = e0 + e1 + e2 + e3;
            ss += dppf<0xB1>(ss);
            ss += dppf<0x4E>(ss);
            float inv = __builtin_amdgcn_rcpf(ss);
            float* rt = &route_s[sq * 128 + si];
            rt[(sj * 4 + 0) * 8] = e0 * inv;
            rt[(sj * 4 + 1) * 8] = e1 * inv;
            rt[(sj * 4 + 2) * 8] = e2 * inv;
            rt[(sj * 4 + 3) * 8] = e3 * inv;
        }
        __syncthreads();

        #pragma unroll
        for (int q = 0; q < 8; ++q) {
            const f32x4* rp = (const f32x4*)&route_s[q * 128 + o * 8];
            f32x4 ra = rp[0], rb2 = rp[1];
            float pre = bias_r
                + ra[0] * v[q][0] + ra[1] * v[q][1] + ra[2] * v[q][2] + ra[3] * v[q][3]
                + rb2[0] * v[q][4] + rb2[1] * v[q][5] + rb2[2] * v[q][6] + rb2[3] * v[q][7];
            float n2 = sum16(pre * pre);
            float act = pre * sqrtf(n2) * __builtin_amdgcn_rcpf(1.0f + n2);
            act_r[q] = act;
            if (it == 1) agree(v[q], act, q, false);
        }
        if (it == 1) __syncthreads();
    }

    // ---- output [b',h0,w0base+q,o,d]
    #pragma unroll
    for (int q = 0; q < 8; ++q)
        outg[((bp * 32 + h0) * 32 + (w0base + q)) * 256 + t] = act_r[q];
}

extern "C" void kernel_launch(void* const* d_in, const int* in_sizes, int n_in,
                              void* d_out, int out_size, void* d_ws, size_t ws_size,
                              hipStream_t stream) {
    const float* x = (const float*)d_in[0];
    const float* w = (const float*)d_in[1];
    const float* b = (const float*)d_in[2];
    float* out = (float*)d_out;

    _Float16* bh = (_Float16*)d_ws;            // 52*256*8*2 = 106496 B

    hipLaunchKernelGGL(prep_w, dim3(416), dim3(256), 0, stream, w, bh);
    hipLaunchKernelGGL(caps_mfma_kernel, dim3(2048), dim3(256), 0, stream,
                       x, bh, b, out);
}

// Round 13
// 110.501 us; speedup vs baseline: 1.2817x; 1.0096x over previous
//
#include <hip/hip_runtime.h>
#include <math.h>

// ConvCapsuleLayer fused: MFMA single-fp16 conv + register-resident routing.
// R13: R12 + LDS bank-conflict fix. R12's counters showed 5.34M conflict
// cycles (17% of kernel): the A-tile i-stride 976 halves = 488 dwords == 8
// (mod 32) put all 8 ia rows in 4 bank-groups -> every conv ds_read_b128 ran
// at 2x. Stride padded to 1032 halves (516 dwords == 4 mod 32) -> ia rows
// spread over all 32 banks; staging b64 writes fixed by the same change.
// Batch scramble (faithful to reference reshape): i_x = b'>>1, b_x=((b'&1)<<3)+i.

typedef __attribute__((ext_vector_type(8))) _Float16 half8;
typedef __attribute__((ext_vector_type(4))) _Float16 half4;
typedef __attribute__((ext_vector_type(4))) float f32x4;

#define IA_STRIDE 1032   // halves per i-row: 516 dwords == 4 (mod 32)

// W [400][256] fp32 -> Bh [52 kgroups][256 n][8 k] fp16, k padded 400->416.
__global__ void prep_w(const float* __restrict__ wg, _Float16* __restrict__ bh) {
    int k = blockIdx.x;        // 0..415
    int n = threadIdx.x;       // 0..255
    float f = (k < 400) ? wg[k * 256 + n] : 0.0f;
    bh[(k >> 3) * 2048 + n * 8 + (k & 7)] = (_Float16)f;
}

// DPP helpers: 0xB1 = quad_perm xor1, 0x4E = xor2, 0x124 = row_ror:4,
// 0x128 = row_ror:8 (== xor8 on the 16-lane ring).
template<int CTRL>
__device__ __forceinline__ float dppf(float x) {
    return __int_as_float(__builtin_amdgcn_update_dpp(
        0, __float_as_int(x), CTRL, 0xF, 0xF, true));
}
__device__ __forceinline__ float sum16(float x) {
    x += dppf<0xB1>(x);
    x += dppf<0x4E>(x);
    x += dppf<0x124>(x);
    x += dppf<0x128>(x);
    return x;
}

__global__ __launch_bounds__(256, 4) void caps_mfma_kernel(
    const float* __restrict__ xg,        // [16,32,32,8,16]
    const _Float16* __restrict__ bhg,    // [52][256][8]
    const float* __restrict__ bg,        // [256]
    float* __restrict__ outg)            // [16,32,32,16,16]
{
    __shared__ __align__(16) char buf[16512];  // xs (16512 B) / vt (16384 B)
    __shared__ float logit_s[1024];            // [q8][i8][o16]
    __shared__ float route_s[1024];            // [q8][o16][i8] (transposed)

    _Float16* xs = (_Float16*)buf;             // [i8][rc 60][c16], stride 1032
    float*    vt = (float*)buf;                // votes^T [n256][r16], swizzled

    const int t      = threadIdx.x;
    const int blk    = blockIdx.x;             // 2048
    const int wt     = blk & 3;
    const int h0     = (blk >> 2) & 31;
    const int bp     = blk >> 7;
    const int w0base = wt << 3;
    const int i_x    = bp >> 1;
    const int bbase  = (bp & 1) << 3;

    const float bias_r = bg[t];

    // ---- stage x window (60 rc x 16 c x 8 i = 7680 floats) as 1920 float4
    const float4* x4 = (const float4*)xg;
    #pragma unroll
    for (int kk = 0; kk < 8; ++kk) {
        int idx4 = t + (kk << 8);
        if (idx4 < 1920) {
            int c2 = idx4 & 3;                 // c = c2*4
            int i  = (idx4 >> 2) & 7;
            int rc = idx4 >> 5;                // 0..59 = r*12 + cc
            int r  = rc / 12;
            int cc = rc - r * 12;
            int hh = h0 + r - 2;
            int ww = w0base + cc - 2;
            float4 f = make_float4(0.f, 0.f, 0.f, 0.f);
            if (hh >= 0 && hh < 32 && ww >= 0 && ww < 32)
                f = x4[((((bbase + i) * 32 + hh) * 32 + ww) * 8 + i_x) * 4 + c2];
            half4 h4;
            h4.x = (_Float16)f.x; h4.y = (_Float16)f.y;
            h4.z = (_Float16)f.z; h4.w = (_Float16)f.w;
            *(half4*)&xs[i * IA_STRIDE + rc * 16 + c2 * 4] = h4;
        }
    }
    __syncthreads();

    // ---- MFMA conv (unpipelined chunk loop, R7 style)
    const int wv   = t >> 6;
    const int lane = t & 63;
    const int lrow = lane & 15;     // m (and n) index within 16-tile
    const int h8   = lane >> 4;     // k-quarter 0..3
    const int ia   = lrow & 7;      // i of this A row
    const int qh   = lrow >> 3;     // q parity

    f32x4 acc[4][4];
    #pragma unroll
    for (int ms = 0; ms < 4; ++ms)
        #pragma unroll
        for (int nt = 0; nt < 4; ++nt)
            acc[ms][nt] = (f32x4){0.f, 0.f, 0.f, 0.f};

    const half8* bhp = (const half8*)bhg;   // [52][256] half8

#define CONV_CHUNK(CH, TAIL)                                                   \
    {                                                                          \
        int k0 = (CH) * 32 + h8 * 8;                                           \
        int p  = k0 >> 4;                                                      \
        int kh = p / 5;                                                        \
        int kw = p - kh * 5;                                                   \
        int abase = ia * IA_STRIDE + (kh * 12 + kw + qh) * 16 + (k0 & 15);     \
        int g = (CH) * 4 + h8;                                                 \
        half8 bhv[4];                                                          \
        _Pragma("unroll")                                                      \
        for (int nt = 0; nt < 4; ++nt)                                         \
            bhv[nt] = bhp[g * 256 + wv * 64 + nt * 16 + lrow];                 \
        _Pragma("unroll")                                                      \
        for (int ms = 0; ms < 4; ++ms) {                                       \
            half8 ahv;                                                         \
            if (!(TAIL) || h8 < 2) ahv = *(const half8*)&xs[abase + ms * 32];  \
            else                   ahv = (half8)(_Float16)0.f;                 \
            _Pragma("unroll")                                                  \
            for (int nt = 0; nt < 4; ++nt)                                     \
                acc[ms][nt] = __builtin_amdgcn_mfma_f32_16x16x32_f16(          \
                    ahv, bhv[nt], acc[ms][nt], 0, 0, 0);                       \
        }                                                                      \
    }

    #pragma unroll
    for (int ch = 0; ch < 12; ++ch) CONV_CHUNK(ch, false)
    CONV_CHUNK(12, true)
#undef CONV_CHUNK

    // ---- transpose acc -> v[q][i] regs, 4 passes of 16 rows via 16 KB vt.
    // Pass ms: rows r_local = h8*4+reg; vt dword addr = n*16 + ((rb^(n&3))<<2).
    float v[8][8];
    #pragma unroll
    for (int ms = 0; ms < 4; ++ms) {
        __syncthreads();                       // xs / previous-pass reads done
        #pragma unroll
        for (int nt = 0; nt < 4; ++nt) {
            int n = wv * 64 + nt * 16 + lrow;
            *(f32x4*)&vt[n * 16 + ((h8 ^ (n & 3)) << 2)] = acc[ms][nt];
        }
        __syncthreads();
        #pragma unroll
        for (int rb = 0; rb < 4; ++rb) {
            f32x4 x = *(const f32x4*)&vt[t * 16 + ((rb ^ (t & 3)) << 2)];
            int q  = ms * 2 + (rb >> 1);
            int ib = (rb & 1) * 4;
            v[q][ib + 0] = x[0];
            v[q][ib + 1] = x[1];
            v[q][ib + 2] = x[2];
            v[q][ib + 3] = x[3];
        }
    }

    // ---- routing from registers: thread t owns od=t (o=t>>4, d=t&15).
    const int o = t >> 4;
    const int d = t & 15;
    const bool b8  = (d & 8) != 0;
    const bool b2v = (d & 2) != 0;
    const bool b1v = (d & 1) != 0;
    const int  im  = (b8 ? 4 : 0) + (b2v ? 2 : 0) + (b1v ? 1 : 0);
    const bool wr  = (d & 4) == 0;
    float act_r[8];

    // agreement: 8 dot-sums over 16 lanes; DPP reduce-scatter, one ds_swizzle
    auto agree = [&](const float* vq, float act, int q, bool first) {
        float p[8];
        #pragma unroll
        for (int i = 0; i < 8; ++i) p[i] = vq[i] * act;
        float s4[4];
        #pragma unroll
        for (int j = 0; j < 4; ++j) {          // exchange lane^8 (ror8)
            float send = b8 ? p[j] : p[j + 4];
            float rcv  = dppf<0x128>(send);
            s4[j] = (b8 ? p[j + 4] : p[j]) + rcv;
        }
        float s2[2];
        #pragma unroll
        for (int j = 0; j < 2; ++j) {          // exchange lane^2
            float send = b2v ? s4[j] : s4[j + 2];
            float rcv  = dppf<0x4E>(send);
            s2[j] = (b2v ? s4[j + 2] : s4[j]) + rcv;
        }
        float send = b1v ? s2[0] : s2[1];      // exchange lane^1
        float rcv  = dppf<0xB1>(send);
        float s1 = (b1v ? s2[1] : s2[0]) + rcv;
        // final: exchange lane^4 (the one non-DPP involution) via ds_swizzle
        float L = s1 + __int_as_float(
            __builtin_amdgcn_ds_swizzle(__float_as_int(s1), 0x101F));
        if (wr) {
            float* dst = &logit_s[q * 128 + im * 16 + o];
            if (first) *dst = L; else *dst += L;
        }
    };

    // ---- it = 0: route == 1/16 exactly; logits written with '=' (no init).
    #pragma unroll
    for (int q = 0; q < 8; ++q) {
        float s = 0.0f;
        #pragma unroll
        for (int i = 0; i < 8; ++i) s += v[q][i];
        float pre = bias_r + 0.0625f * s;
        float n2 = sum16(pre * pre);
        float act = pre * sqrtf(n2) * __builtin_amdgcn_rcpf(1.0f + n2);
        act_r[q] = act;
        agree(v[q], act, q, true);
    }
    __syncthreads();

    // ---- it = 1, 2
    #pragma unroll
    for (int it = 1; it < 3; ++it) {
        {   // parallel softmax: thread -> row r = t>>2 (q=r>>3,i=r&7), 4 o's
            int rr = t >> 2, sq = rr >> 3, si = rr & 7, sj = t & 3;
            f32x4 lg = *(const f32x4*)&logit_s[rr * 16 + sj * 4];
            float m = fmaxf(fmaxf(lg[0], lg[1]), fmaxf(lg[2], lg[3]));
            m = fmaxf(m, dppf<0xB1>(m));       // quad max (4 lanes = same row)
            m = fmaxf(m, dppf<0x4E>(m));
            float e0 = __expf(lg[0] - m), e1 = __expf(lg[1] - m);
            float e2 = __expf(lg[2] - m), e3 = __expf(lg[3] - m);
            float ss = e0 + e1 + e2 + e3;
            ss += dppf<0xB1>(ss);
            ss += dppf<0x4E>(ss);
            float inv = __builtin_amdgcn_rcpf(ss);
            float* rt = &route_s[sq * 128 + si];
            rt[(sj * 4 + 0) * 8] = e0 * inv;
            rt[(sj * 4 + 1) * 8] = e1 * inv;
            rt[(sj * 4 + 2) * 8] = e2 * inv;
            rt[(sj * 4 + 3) * 8] = e3 * inv;
        }
        __syncthreads();

        #pragma unroll
        for (int q = 0; q < 8; ++q) {
            const f32x4* rp = (const f32x4*)&route_s[q * 128 + o * 8];
            f32x4 ra = rp[0], rb2 = rp[1];
            float pre = bias_r
                + ra[0] * v[q][0] + ra[1] * v[q][1] + ra[2] * v[q][2] + ra[3] * v[q][3]
                + rb2[0] * v[q][4] + rb2[1] * v[q][5] + rb2[2] * v[q][6] + rb2[3] * v[q][7];
            float n2 = sum16(pre * pre);
            float act = pre * sqrtf(n2) * __builtin_amdgcn_rcpf(1.0f + n2);
            act_r[q] = act;
            if (it == 1) agree(v[q], act, q, false);
        }
        if (it == 1) __syncthreads();
    }

    // ---- output [b',h0,w0base+q,o,d]
    #pragma unroll
    for (int q = 0; q < 8; ++q)
        outg[((bp * 32 + h0) * 32 + (w0base + q)) * 256 + t] = act_r[q];
}

extern "C" void kernel_launch(void* const* d_in, const int* in_sizes, int n_in,
                              void* d_out, int out_size, void* d_ws, size_t ws_size,
                              hipStream_t stream) {
    const float* x = (const float*)d_in[0];
    const float* w = (const float*)d_in[1];
    const float* b = (const float*)d_in[2];
    float* out = (float*)d_out;

    _Float16* bh = (_Float16*)d_ws;            // 52*256*8*2 = 106496 B

    hipLaunchKernelGGL(prep_w, dim3(416), dim3(256), 0, stream, w, bh);
    hipLaunchKernelGGL(caps_mfma_kernel, dim3(2048), dim3(256), 0, stream,
                       x, bh, b, out);
}